// Round 1
// baseline (1029.350 us; speedup 1.0000x reference)
//
#include <hip/hip_runtime.h>

// GraphSAGE 2-layer, N=100000 nodes, d=64, E=1.6M edges, fp32.
// Strategy: per layer, out = relu( (scatter_sum(x)[i] @ Wl^T) * inv_cnt[i] + b + x@Wr^T )
//   -> dense GEMM for Z = X@Wl^T and P = X@Wr^T + b, then CSR gather-mean.
// CSR built once per call (graph identical for both layers).

#define NFEAT 64
#define GR 8  // rows per wave in GEMM

// ---------------- CSR build ----------------

__global__ __launch_bounds__(256) void count_k(const int* __restrict__ dst,
                                               int* __restrict__ cnt, int E) {
  int i = (blockIdx.x * 256 + threadIdx.x) * 4;
  if (i + 3 < E) {
    int4 d = *(const int4*)(dst + i);
    atomicAdd(&cnt[d.x], 1); atomicAdd(&cnt[d.y], 1);
    atomicAdd(&cnt[d.z], 1); atomicAdd(&cnt[d.w], 1);
  } else {
    for (int e = i; e < E; ++e) atomicAdd(&cnt[dst[e]], 1);
  }
}

__global__ __launch_bounds__(256) void scan_blocks(const int* __restrict__ cnt,
                                                   int* __restrict__ off,
                                                   int* __restrict__ bsum, int n) {
  __shared__ int s[256];
  int tid = threadIdx.x;
  int i = blockIdx.x * 256 + tid;
  int v = (i < n) ? cnt[i] : 0;
  s[tid] = v;
  __syncthreads();
  for (int d = 1; d < 256; d <<= 1) {
    int add = (tid >= d) ? s[tid - d] : 0;
    __syncthreads();
    s[tid] += add;
    __syncthreads();
  }
  if (i < n) off[i] = s[tid] - v;        // block-local exclusive prefix
  if (tid == 255) bsum[blockIdx.x] = s[255];
}

__global__ __launch_bounds__(512) void scan_top(const int* __restrict__ bsum,
                                                int* __restrict__ boff, int nb) {
  __shared__ int s[512];
  int t = threadIdx.x;
  int v = (t < nb) ? bsum[t] : 0;
  s[t] = v;
  __syncthreads();
  for (int d = 1; d < 512; d <<= 1) {
    int add = (t >= d) ? s[t - d] : 0;
    __syncthreads();
    s[t] += add;
    __syncthreads();
  }
  if (t < nb) boff[t] = s[t] - v;        // exclusive prefix of block sums
}

__global__ __launch_bounds__(256) void finalize_k(const int* __restrict__ cnt,
                                                  int* __restrict__ off,
                                                  const int* __restrict__ boff,
                                                  int* __restrict__ cur,
                                                  float* __restrict__ inv, int n) {
  int i = blockIdx.x * 256 + threadIdx.x;
  if (i < n) {
    int o = off[i] + boff[i >> 8];
    off[i] = o;
    cur[i] = o;
    int c = cnt[i];
    inv[i] = 1.0f / (float)(c > 1 ? c : 1);
  }
}

__global__ __launch_bounds__(256) void fill_k(const int* __restrict__ src,
                                              const int* __restrict__ dst,
                                              int* __restrict__ cur,
                                              int* __restrict__ csr, int E) {
  int i = (blockIdx.x * 256 + threadIdx.x) * 4;
  if (i + 3 < E) {
    int4 d = *(const int4*)(dst + i);
    int4 s = *(const int4*)(src + i);
    int p;
    p = atomicAdd(&cur[d.x], 1); csr[p] = s.x;
    p = atomicAdd(&cur[d.y], 1); csr[p] = s.y;
    p = atomicAdd(&cur[d.z], 1); csr[p] = s.z;
    p = atomicAdd(&cur[d.w], 1); csr[p] = s.w;
  } else {
    for (int e = i; e < E; ++e) {
      int p = atomicAdd(&cur[dst[e]], 1);
      csr[p] = src[e];
    }
  }
}

// ---------------- Dense GEMM: Z = X@Wl^T, P = X@Wr^T + b ----------------
// Block = 256 threads = 4 waves; each wave handles GR=8 rows; block = 32 rows.
// Weights staged in LDS with stride 68 (16B aligned, breaks stride-64 bank pattern).

__global__ __launch_bounds__(256) void gemm_k(const float* __restrict__ X,
                                              const float* __restrict__ Wl,
                                              const float* __restrict__ Wr,
                                              const float* __restrict__ b,
                                              float* __restrict__ Z,
                                              float* __restrict__ P, int n) {
  __shared__ float sWl[64 * 68];
  __shared__ float sWr[64 * 68];
  __shared__ float sb[64];
  __shared__ float sx[4 * GR * 64];   // 4 waves x 8 rows x 64 feats

  int tid = threadIdx.x;
  for (int idx = tid; idx < 4096; idx += 256) {
    int r = idx >> 6, k = idx & 63;
    sWl[r * 68 + k] = Wl[idx];
    sWr[r * 68 + k] = Wr[idx];
  }
  if (tid < 64) sb[tid] = b[tid];

  int wave = tid >> 6;
  int lane = tid & 63;
  int row0 = (blockIdx.x * 4 + wave) * GR;

  // stage GR contiguous rows (512 floats) with float4 loads
  if (row0 + GR <= n) {
    const float4* xs = (const float4*)(X + (size_t)row0 * NFEAT);
    float4* sxw = (float4*)(sx + wave * (GR * 64));
    sxw[lane] = xs[lane];
    sxw[lane + 64] = xs[lane + 64];
  } else if (row0 < n) {
    for (int j = 0; j < GR; ++j) {
      if (row0 + j < n) sx[wave * (GR * 64) + j * 64 + lane] = X[(size_t)(row0 + j) * NFEAT + lane];
    }
  }
  __syncthreads();
  if (row0 >= n) return;

  float accz[GR], accp[GR];
#pragma unroll
  for (int j = 0; j < GR; ++j) { accz[j] = 0.0f; accp[j] = sb[lane]; }

  const float* xw = sx + wave * (GR * 64);
#pragma unroll
  for (int kk = 0; kk < 64; kk += 4) {
    float4 wl = *(const float4*)&sWl[lane * 68 + kk];
    float4 wr = *(const float4*)&sWr[lane * 68 + kk];
#pragma unroll
    for (int j = 0; j < GR; ++j) {
      float4 xk = *(const float4*)&xw[j * 64 + kk];   // broadcast read
      accz[j] += xk.x * wl.x + xk.y * wl.y + xk.z * wl.z + xk.w * wl.w;
      accp[j] += xk.x * wr.x + xk.y * wr.y + xk.z * wr.z + xk.w * wr.w;
    }
  }

#pragma unroll
  for (int j = 0; j < GR; ++j) {
    int r = row0 + j;
    if (r < n) {
      Z[(size_t)r * NFEAT + lane] = accz[j];
      P[(size_t)r * NFEAT + lane] = accp[j];
    }
  }
}

// ---------------- CSR gather-mean + epilogue ----------------
// One wave per node. 4 groups of 16 lanes each process one neighbor (float4/lane),
// xor-shuffle reduce across groups, group 0 writes relu(acc*inv + P).

__global__ __launch_bounds__(256) void agg_k(const int* __restrict__ off,
                                             const int* __restrict__ cnt,
                                             const float* __restrict__ inv,
                                             const int* __restrict__ csr,
                                             const float* __restrict__ Z,
                                             const float* __restrict__ Pin,
                                             float* __restrict__ out, int n) {
  int node = (blockIdx.x * 256 + threadIdx.x) >> 6;
  if (node >= n) return;
  int lane = threadIdx.x & 63;
  int g = lane >> 4;
  int q = lane & 15;

  int start = off[node];
  int deg = cnt[node];

  float ax = 0.f, ay = 0.f, az = 0.f, aw = 0.f;
  for (int j = g; j < deg; j += 4) {
    int nb = csr[start + j];
    float4 v = *(const float4*)&Z[(size_t)nb * NFEAT + q * 4];
    ax += v.x; ay += v.y; az += v.z; aw += v.w;
  }

  // reduce the 4 groups (lanes differing in bits 4,5)
  ax += __shfl_xor(ax, 16); ay += __shfl_xor(ay, 16);
  az += __shfl_xor(az, 16); aw += __shfl_xor(aw, 16);
  ax += __shfl_xor(ax, 32); ay += __shfl_xor(ay, 32);
  az += __shfl_xor(az, 32); aw += __shfl_xor(aw, 32);

  if (g == 0) {
    float iv = inv[node];
    float4 p = *(const float4*)&Pin[(size_t)node * NFEAT + q * 4];
    float4 r;
    r.x = fmaxf(ax * iv + p.x, 0.f);
    r.y = fmaxf(ay * iv + p.y, 0.f);
    r.z = fmaxf(az * iv + p.z, 0.f);
    r.w = fmaxf(aw * iv + p.w, 0.f);
    *(float4*)&out[(size_t)node * NFEAT + q * 4] = r;
  }
}

// ---------------- launcher ----------------

extern "C" void kernel_launch(void* const* d_in, const int* in_sizes, int n_in,
                              void* d_out, int out_size, void* d_ws, size_t ws_size,
                              hipStream_t stream) {
  const float* x   = (const float*)d_in[0];
  const int*   ei  = (const int*)d_in[1];
  const float* W1l = (const float*)d_in[2];
  const float* b1  = (const float*)d_in[3];
  const float* W1r = (const float*)d_in[4];
  const float* W2l = (const float*)d_in[5];
  const float* b2  = (const float*)d_in[6];
  const float* W2r = (const float*)d_in[7];
  float* out = (float*)d_out;

  int N = in_sizes[0] / NFEAT;     // 100000
  int E = in_sizes[1] / 2;         // 1600000
  const int* srcp = ei;
  const int* dstp = ei + E;

  char* w = (char*)d_ws;
  int*   cnt  = (int*)w;   w += (size_t)N * 4;
  int*   off  = (int*)w;   w += (size_t)N * 4;
  int*   cur  = (int*)w;   w += (size_t)N * 4;
  float* inv  = (float*)w; w += (size_t)N * 4;
  int*   bsum = (int*)w;   w += 512 * 4;
  int*   boff = (int*)w;   w += 512 * 4;
  int*   csr  = (int*)w;   w += (size_t)E * 4;
  float* Z    = (float*)w; w += (size_t)N * NFEAT * 4;
  float* H    = (float*)w; w += (size_t)N * NFEAT * 4;
  if ((size_t)(w - (char*)d_ws) > ws_size) return;  // workspace too small

  hipMemsetAsync(cnt, 0, (size_t)N * 4, stream);

  int eb = ((E + 3) / 4 + 255) / 256;
  int nb = (N + 255) / 256;

  count_k<<<eb, 256, 0, stream>>>(dstp, cnt, E);
  scan_blocks<<<nb, 256, 0, stream>>>(cnt, off, bsum, N);
  scan_top<<<1, 512, 0, stream>>>(bsum, boff, nb);
  finalize_k<<<nb, 256, 0, stream>>>(cnt, off, boff, cur, inv, N);
  fill_k<<<eb, 256, 0, stream>>>(srcp, dstp, cur, csr, E);

  int gb = (N + 4 * GR - 1) / (4 * GR);
  int ab = (N + 3) / 4;

  // layer 1: Z = x@W1l^T -> ws.Z ; P = x@W1r^T + b1 -> d_out ; H = relu(...)
  gemm_k<<<gb, 256, 0, stream>>>(x, W1l, W1r, b1, Z, out, N);
  agg_k<<<ab, 256, 0, stream>>>(off, cnt, inv, csr, Z, out, H, N);
  // layer 2: Z = H@W2l^T ; P -> d_out ; final -> d_out (row-wise in-place, safe)
  gemm_k<<<gb, 256, 0, stream>>>(H, W2l, W2r, b2, Z, out, N);
  agg_k<<<ab, 256, 0, stream>>>(off, cnt, inv, csr, Z, out, out, N);
}

// Round 2
// 535.958 us; speedup vs baseline: 1.9206x; 1.9206x over previous
//
#include <hip/hip_runtime.h>

// GraphSAGE 2-layer, N=100000 nodes, d=64, E=1.6M edges, fp32.
// Strategy: per layer, out = relu( (scatter_sum(x)[i] @ Wl^T) * inv_cnt[i] + b + x@Wr^T )
//   -> dense GEMM for Z = X@Wl^T and P = X@Wr^T + b, then CSR gather-mean.
// CSR built once per call (graph identical for both layers).

#define NFEAT 64
#define GR 8  // rows per wave in GEMM

// ---------------- CSR build ----------------

__global__ __launch_bounds__(256) void count_k(const int* __restrict__ dst,
                                               int* __restrict__ cnt, int E) {
  int i = (blockIdx.x * 256 + threadIdx.x) * 4;
  if (i + 3 < E) {
    int4 d = *(const int4*)(dst + i);
    atomicAdd(&cnt[d.x], 1); atomicAdd(&cnt[d.y], 1);
    atomicAdd(&cnt[d.z], 1); atomicAdd(&cnt[d.w], 1);
  } else {
    for (int e = i; e < E; ++e) atomicAdd(&cnt[dst[e]], 1);
  }
}

__global__ __launch_bounds__(256) void scan_blocks(const int* __restrict__ cnt,
                                                   int* __restrict__ off,
                                                   int* __restrict__ bsum, int n) {
  __shared__ int s[256];
  int tid = threadIdx.x;
  int i = blockIdx.x * 256 + tid;
  int v = (i < n) ? cnt[i] : 0;
  s[tid] = v;
  __syncthreads();
  for (int d = 1; d < 256; d <<= 1) {
    int add = (tid >= d) ? s[tid - d] : 0;
    __syncthreads();
    s[tid] += add;
    __syncthreads();
  }
  if (i < n) off[i] = s[tid] - v;        // block-local exclusive prefix
  if (tid == 255) bsum[blockIdx.x] = s[255];
}

__global__ __launch_bounds__(512) void scan_top(const int* __restrict__ bsum,
                                                int* __restrict__ boff, int nb) {
  __shared__ int s[512];
  int t = threadIdx.x;
  int v = (t < nb) ? bsum[t] : 0;
  s[t] = v;
  __syncthreads();
  for (int d = 1; d < 512; d <<= 1) {
    int add = (t >= d) ? s[t - d] : 0;
    __syncthreads();
    s[t] += add;
    __syncthreads();
  }
  if (t < nb) boff[t] = s[t] - v;        // exclusive prefix of block sums
}

__global__ __launch_bounds__(256) void finalize_k(const int* __restrict__ cnt,
                                                  int* __restrict__ off,
                                                  const int* __restrict__ boff,
                                                  int* __restrict__ cur,
                                                  float* __restrict__ inv, int n) {
  int i = blockIdx.x * 256 + threadIdx.x;
  if (i < n) {
    int o = off[i] + boff[i >> 8];
    off[i] = o;
    cur[i] = o;
    int c = cnt[i];
    inv[i] = 1.0f / (float)(c > 1 ? c : 1);
  }
}

__global__ __launch_bounds__(256) void fill_k(const int* __restrict__ src,
                                              const int* __restrict__ dst,
                                              int* __restrict__ cur,
                                              int* __restrict__ csr, int E) {
  int i = (blockIdx.x * 256 + threadIdx.x) * 4;
  if (i + 3 < E) {
    int4 d = *(const int4*)(dst + i);
    int4 s = *(const int4*)(src + i);
    int p;
    p = atomicAdd(&cur[d.x], 1); csr[p] = s.x;
    p = atomicAdd(&cur[d.y], 1); csr[p] = s.y;
    p = atomicAdd(&cur[d.z], 1); csr[p] = s.z;
    p = atomicAdd(&cur[d.w], 1); csr[p] = s.w;
  } else {
    for (int e = i; e < E; ++e) {
      int p = atomicAdd(&cur[dst[e]], 1);
      csr[p] = src[e];
    }
  }
}

// ---------------- Dense GEMM: Z = X@Wl^T, P = X@Wr^T + b ----------------
// Block = 256 threads = 4 waves; each wave handles GR=8 rows; block = 32 rows.
// W stored TRANSPOSED in LDS ([k][o], lane=o): consecutive-lane reads -> 2-way
// aliasing only (free per m136). kk loop kept at unroll 2 to avoid the R1
// register spill (VGPR=256, 540MB scratch traffic).

__global__ __launch_bounds__(256) void gemm_k(const float* __restrict__ X,
                                              const float* __restrict__ Wl,
                                              const float* __restrict__ Wr,
                                              const float* __restrict__ b,
                                              float* __restrict__ Z,
                                              float* __restrict__ P, int n) {
  __shared__ float sWl[64 * 64];   // transposed: sWl[k*64+o] = Wl[o][k]
  __shared__ float sWr[64 * 64];
  __shared__ float sb[64];
  __shared__ float sx[4 * GR * 64];   // 4 waves x 8 rows x 64 feats

  int tid = threadIdx.x;
  // o fast within a wave -> conflict-free LDS writes; global read is strided
  // but only 32KB/block from L2 (one-time).
  for (int idx = tid; idx < 4096; idx += 256) {
    int k = idx >> 6, o = idx & 63;
    sWl[k * 64 + o] = Wl[o * 64 + k];
    sWr[k * 64 + o] = Wr[o * 64 + k];
  }
  if (tid < 64) sb[tid] = b[tid];

  int wave = tid >> 6;
  int lane = tid & 63;
  int row0 = (blockIdx.x * 4 + wave) * GR;

  // stage GR contiguous rows (512 floats) with float4 loads
  if (row0 + GR <= n) {
    const float4* xs = (const float4*)(X + (size_t)row0 * NFEAT);
    float4* sxw = (float4*)(sx + wave * (GR * 64));
    sxw[lane] = xs[lane];
    sxw[lane + 64] = xs[lane + 64];
  } else if (row0 < n) {
    for (int j = 0; j < GR; ++j) {
      if (row0 + j < n) sx[wave * (GR * 64) + j * 64 + lane] = X[(size_t)(row0 + j) * NFEAT + lane];
    }
  }
  __syncthreads();
  if (row0 >= n) return;

  float accz[GR], accp[GR];
#pragma unroll
  for (int j = 0; j < GR; ++j) { accz[j] = 0.0f; accp[j] = sb[lane]; }

  const float* xw = sx + wave * (GR * 64);
#pragma unroll 2
  for (int kk = 0; kk < 64; kk += 4) {
    float wl0 = sWl[(kk + 0) * 64 + lane];
    float wl1 = sWl[(kk + 1) * 64 + lane];
    float wl2 = sWl[(kk + 2) * 64 + lane];
    float wl3 = sWl[(kk + 3) * 64 + lane];
    float wr0 = sWr[(kk + 0) * 64 + lane];
    float wr1 = sWr[(kk + 1) * 64 + lane];
    float wr2 = sWr[(kk + 2) * 64 + lane];
    float wr3 = sWr[(kk + 3) * 64 + lane];
#pragma unroll
    for (int j = 0; j < GR; ++j) {
      float4 xk = *(const float4*)&xw[j * 64 + kk];   // wave-uniform broadcast
      accz[j] += xk.x * wl0 + xk.y * wl1 + xk.z * wl2 + xk.w * wl3;
      accp[j] += xk.x * wr0 + xk.y * wr1 + xk.z * wr2 + xk.w * wr3;
    }
  }

#pragma unroll
  for (int j = 0; j < GR; ++j) {
    int r = row0 + j;
    if (r < n) {
      Z[(size_t)r * NFEAT + lane] = accz[j];
      P[(size_t)r * NFEAT + lane] = accp[j];
    }
  }
}

// ---------------- CSR gather-mean + epilogue ----------------
// One wave per node. 4 groups of 16 lanes each process one neighbor (float4/lane),
// xor-shuffle reduce across groups, group 0 writes relu(acc*inv + P).

__global__ __launch_bounds__(256) void agg_k(const int* __restrict__ off,
                                             const int* __restrict__ cnt,
                                             const float* __restrict__ inv,
                                             const int* __restrict__ csr,
                                             const float* __restrict__ Z,
                                             const float* __restrict__ Pin,
                                             float* __restrict__ out, int n) {
  int node = (blockIdx.x * 256 + threadIdx.x) >> 6;
  if (node >= n) return;
  int lane = threadIdx.x & 63;
  int g = lane >> 4;
  int q = lane & 15;

  int start = off[node];
  int deg = cnt[node];

  float ax = 0.f, ay = 0.f, az = 0.f, aw = 0.f;
  for (int j = g; j < deg; j += 4) {
    int nb = csr[start + j];
    float4 v = *(const float4*)&Z[(size_t)nb * NFEAT + q * 4];
    ax += v.x; ay += v.y; az += v.z; aw += v.w;
  }

  // reduce the 4 groups (lanes differing in bits 4,5)
  ax += __shfl_xor(ax, 16); ay += __shfl_xor(ay, 16);
  az += __shfl_xor(az, 16); aw += __shfl_xor(aw, 16);
  ax += __shfl_xor(ax, 32); ay += __shfl_xor(ay, 32);
  az += __shfl_xor(az, 32); aw += __shfl_xor(aw, 32);

  if (g == 0) {
    float iv = inv[node];
    float4 p = *(const float4*)&Pin[(size_t)node * NFEAT + q * 4];
    float4 r;
    r.x = fmaxf(ax * iv + p.x, 0.f);
    r.y = fmaxf(ay * iv + p.y, 0.f);
    r.z = fmaxf(az * iv + p.z, 0.f);
    r.w = fmaxf(aw * iv + p.w, 0.f);
    *(float4*)&out[(size_t)node * NFEAT + q * 4] = r;
  }
}

// ---------------- launcher ----------------

extern "C" void kernel_launch(void* const* d_in, const int* in_sizes, int n_in,
                              void* d_out, int out_size, void* d_ws, size_t ws_size,
                              hipStream_t stream) {
  const float* x   = (const float*)d_in[0];
  const int*   ei  = (const int*)d_in[1];
  const float* W1l = (const float*)d_in[2];
  const float* b1  = (const float*)d_in[3];
  const float* W1r = (const float*)d_in[4];
  const float* W2l = (const float*)d_in[5];
  const float* b2  = (const float*)d_in[6];
  const float* W2r = (const float*)d_in[7];
  float* out = (float*)d_out;

  int N = in_sizes[0] / NFEAT;     // 100000
  int E = in_sizes[1] / 2;         // 1600000
  const int* srcp = ei;
  const int* dstp = ei + E;

  char* w = (char*)d_ws;
  int*   cnt  = (int*)w;   w += (size_t)N * 4;
  int*   off  = (int*)w;   w += (size_t)N * 4;
  int*   cur  = (int*)w;   w += (size_t)N * 4;
  float* inv  = (float*)w; w += (size_t)N * 4;
  int*   bsum = (int*)w;   w += 512 * 4;
  int*   boff = (int*)w;   w += 512 * 4;
  int*   csr  = (int*)w;   w += (size_t)E * 4;
  float* Z    = (float*)w; w += (size_t)N * NFEAT * 4;
  float* H    = (float*)w; w += (size_t)N * NFEAT * 4;
  if ((size_t)(w - (char*)d_ws) > ws_size) return;  // workspace too small

  hipMemsetAsync(cnt, 0, (size_t)N * 4, stream);

  int eb = ((E + 3) / 4 + 255) / 256;
  int nb = (N + 255) / 256;

  count_k<<<eb, 256, 0, stream>>>(dstp, cnt, E);
  scan_blocks<<<nb, 256, 0, stream>>>(cnt, off, bsum, N);
  scan_top<<<1, 512, 0, stream>>>(bsum, boff, nb);
  finalize_k<<<nb, 256, 0, stream>>>(cnt, off, boff, cur, inv, N);
  fill_k<<<eb, 256, 0, stream>>>(srcp, dstp, cur, csr, E);

  int gb = (N + 4 * GR - 1) / (4 * GR);
  int ab = (N + 3) / 4;

  // layer 1: Z = x@W1l^T -> ws.Z ; P = x@W1r^T + b1 -> d_out ; H = relu(...)
  gemm_k<<<gb, 256, 0, stream>>>(x, W1l, W1r, b1, Z, out, N);
  agg_k<<<ab, 256, 0, stream>>>(off, cnt, inv, csr, Z, out, H, N);
  // layer 2: Z = H@W2l^T ; P -> d_out ; final -> d_out (row-wise in-place, safe)
  gemm_k<<<gb, 256, 0, stream>>>(H, W2l, W2r, b2, Z, out, N);
  agg_k<<<ab, 256, 0, stream>>>(off, cnt, inv, csr, Z, out, out, N);
}